// Round 1
// baseline (617.219 us; speedup 1.0000x reference)
//
#include <hip/hip_runtime.h>

#define NROWS 65536
#define DK 256
#define NCODES 1024
#define FLAG_CAP 8192
#define MARGIN 1e-2f

#define Q_OFF   0
#define LOSS_OFF 16777216
#define IDX_OFF  16777217

// ---------------- ws layout (bytes) ----------------
// 0      : int    flag_count
// 8      : double loss_part[64]
// 520    : double enorm_d[1024]
// 8712   : float  enorm_f[1024]
// 12808  : int    flag_rows[FLAG_CAP]
// 45576  : int    idx_ws[65536]
// total ~ 307720 bytes

__global__ __launch_bounds__(256) void init_kernel(
    const float* __restrict__ E, double* __restrict__ enorm_d,
    float* __restrict__ enorm_f, int* __restrict__ flag_count,
    double* __restrict__ loss_part) {
  const int c = blockIdx.x * 256 + threadIdx.x;  // 0..1023
  if (blockIdx.x == 0) {
    if (threadIdx.x == 0) *flag_count = 0;
    if (threadIdx.x < 64) loss_part[threadIdx.x] = 0.0;
  }
  double s = 0.0;
  for (int k = 0; k < DK; ++k) {
    const double v = (double)E[(size_t)c * DK + k];
    s += v * v;
  }
  enorm_d[c] = s;
  enorm_f[c] = (float)s;
}

// Phase 1: fp32 distance GEMM + per-row top-2 argmin.
// Block = 256 threads (16x16), covers 128 rows x ALL 1024 codes (8 ctiles of 128).
// Per-thread 8x8 register tile; K staged in 32-wide LDS chunks, transposed layout.
__global__ __launch_bounds__(256, 2) void dist_argmin(
    const float* __restrict__ X, const float* __restrict__ E,
    const float* __restrict__ enorm_f, int* __restrict__ idx_ws,
    int* __restrict__ flag_count, int* __restrict__ flag_rows) {
  __shared__ float As[32 * 128];      // [k][row]
  __shared__ float Bs[32 * 128];      // [k][code]
  __shared__ float red_v1[128 * 16];
  __shared__ float red_v2[128 * 16];
  __shared__ int   red_i1[128 * 16];

  const int tid = threadIdx.x;
  const int tx = tid & 15;            // code group
  const int ty = tid >> 4;            // row group
  const int rowBase = blockIdx.x * 128;

  // running top-2 per row, held by threads tid<128 (row = tid)
  float rv1 = 3.0e38f, rv2 = 3.0e38f;
  int ri1 = 0x7fffffff;

  const int rS = tid & 31;            // staging row/code within 32-slice
  const int ks = (tid >> 5) << 2;     // staging k offset (0,4,...,28)

  for (int ct = 0; ct < 8; ++ct) {
    const int codeBase = ct * 128;
    float acc[8][8];
    #pragma unroll
    for (int i = 0; i < 8; ++i)
      #pragma unroll
      for (int j = 0; j < 8; ++j) acc[i][j] = 0.0f;

    for (int kk = 0; kk < 256; kk += 32) {
      __syncthreads();
      #pragma unroll
      for (int rr = 0; rr < 128; rr += 32) {
        const int r = rS + rr;
        const float4 a = *reinterpret_cast<const float4*>(
            &X[(size_t)(rowBase + r) * DK + kk + ks]);
        As[(ks + 0) * 128 + r] = a.x;
        As[(ks + 1) * 128 + r] = a.y;
        As[(ks + 2) * 128 + r] = a.z;
        As[(ks + 3) * 128 + r] = a.w;
        const float4 b = *reinterpret_cast<const float4*>(
            &E[(size_t)(codeBase + r) * DK + kk + ks]);
        Bs[(ks + 0) * 128 + r] = b.x;
        Bs[(ks + 1) * 128 + r] = b.y;
        Bs[(ks + 2) * 128 + r] = b.z;
        Bs[(ks + 3) * 128 + r] = b.w;
      }
      __syncthreads();
      #pragma unroll 4
      for (int k = 0; k < 32; ++k) {
        const float4 a0 = *reinterpret_cast<const float4*>(&As[k * 128 + ty * 8]);
        const float4 a1 = *reinterpret_cast<const float4*>(&As[k * 128 + ty * 8 + 4]);
        const float4 b0 = *reinterpret_cast<const float4*>(&Bs[k * 128 + tx * 8]);
        const float4 b1 = *reinterpret_cast<const float4*>(&Bs[k * 128 + tx * 8 + 4]);
        const float a_[8] = {a0.x, a0.y, a0.z, a0.w, a1.x, a1.y, a1.z, a1.w};
        const float b_[8] = {b0.x, b0.y, b0.z, b0.w, b1.x, b1.y, b1.z, b1.w};
        #pragma unroll
        for (int i = 0; i < 8; ++i)
          #pragma unroll
          for (int j = 0; j < 8; ++j)
            acc[i][j] = fmaf(a_[i], b_[j], acc[i][j]);
      }
    }

    // epilogue: per-thread top-2 over its 8 codes, per row
    #pragma unroll
    for (int i = 0; i < 8; ++i) {
      float v1 = 3.0e38f, v2 = 3.0e38f;
      int i1 = 0x7fffffff;
      #pragma unroll
      for (int j = 0; j < 8; ++j) {
        const int code = codeBase + tx * 8 + j;
        const float d = enorm_f[code] - 2.0f * acc[i][j];
        if (d < v1) { v2 = v1; v1 = d; i1 = code; }
        else if (d < v2) { v2 = d; }
      }
      const int row = ty * 8 + i;
      red_v1[row * 16 + tx] = v1;
      red_v2[row * 16 + tx] = v2;
      red_i1[row * 16 + tx] = i1;
    }
    __syncthreads();
    if (tid < 128) {
      // merge 16 candidate top-2 sets into running top-2 (tx/ct increasing ->
      // strict '<' keeps the lowest index on exact ties; equal values collapse
      // margin to 0 and get flagged for the fp64 pass)
      for (int t2 = 0; t2 < 16; ++t2) {
        const float w1 = red_v1[tid * 16 + t2];
        const float w2 = red_v2[tid * 16 + t2];
        const int j1 = red_i1[tid * 16 + t2];
        if (w1 < rv1) { rv2 = fminf(rv1, w2); rv1 = w1; ri1 = j1; }
        else          { rv2 = fminf(rv2, w1); }
      }
    }
    __syncthreads();
  }

  if (tid < 128) {
    const int row = rowBase + tid;
    idx_ws[row] = ri1;
    if (rv2 - rv1 < MARGIN) {   // fp32 worst-case error ~2e-3 << MARGIN
      const int p = atomicAdd(flag_count, 1);
      if (p < FLAG_CAP) flag_rows[p] = row;
    }
  }
}

// Phase 2: exact fp64 re-resolution of near-tie rows (expected ~50 rows).
__global__ __launch_bounds__(256) void fixup(
    const float* __restrict__ X, const float* __restrict__ E,
    const double* __restrict__ enorm_d, const int* __restrict__ flag_count,
    const int* __restrict__ flag_rows, int* __restrict__ idx_ws) {
  __shared__ float xs[DK];
  __shared__ double rv[256];
  __shared__ int ri[256];
  int cnt = *flag_count;
  if (cnt > FLAG_CAP) cnt = FLAG_CAP;
  for (int f = blockIdx.x; f < cnt; f += gridDim.x) {
    const int row = flag_rows[f];
    __syncthreads();
    xs[threadIdx.x] = X[(size_t)row * DK + threadIdx.x];
    __syncthreads();
    double bestv = 1.0e300;
    int besti = 0x7fffffff;
    for (int c = threadIdx.x; c < NCODES; c += 256) {
      double s = 0.0;
      for (int k = 0; k < DK; ++k)
        s += (double)xs[k] * (double)E[(size_t)c * DK + k];
      const double d = enorm_d[c] - 2.0 * s;
      if (d < bestv || (d == bestv && c < besti)) { bestv = d; besti = c; }
    }
    rv[threadIdx.x] = bestv;
    ri[threadIdx.x] = besti;
    __syncthreads();
    for (int off = 128; off > 0; off >>= 1) {
      if (threadIdx.x < off) {
        const double ov = rv[threadIdx.x + off];
        const int oi = ri[threadIdx.x + off];
        if (ov < rv[threadIdx.x] ||
            (ov == rv[threadIdx.x] && oi < ri[threadIdx.x])) {
          rv[threadIdx.x] = ov;
          ri[threadIdx.x] = oi;
        }
      }
      __syncthreads();
    }
    if (threadIdx.x == 0) idx_ws[row] = ri[0];
  }
}

// Phase 3: gather quantized rows, write indices, accumulate loss in fp64.
__global__ __launch_bounds__(256) void gather_loss(
    const float* __restrict__ X, const float* __restrict__ E,
    const int* __restrict__ idx_ws, float* __restrict__ out,
    double* __restrict__ loss_part) {
  const int t = threadIdx.x;
  double ls = 0.0;
  const int rowBase = blockIdx.x * 16;
  for (int i = 0; i < 16; ++i) {
    const int row = rowBase + i;
    const int idx = idx_ws[row];
    const float q = E[(size_t)idx * DK + t];
    const float x = X[(size_t)row * DK + t];
    out[Q_OFF + (size_t)row * DK + t] = q;   // quantized_st == quantized numerically
    const double df = (double)q - (double)x;
    ls += df * df;
    if (t == 0) out[IDX_OFF + row] = (float)idx;
  }
  for (int o = 32; o > 0; o >>= 1) ls += __shfl_down(ls, o, 64);
  __shared__ double wsum[4];
  if ((t & 63) == 0) wsum[t >> 6] = ls;
  __syncthreads();
  if (t == 0) {
    const double s = wsum[0] + wsum[1] + wsum[2] + wsum[3];
    atomicAdd(&loss_part[blockIdx.x & 63], s);
  }
}

__global__ __launch_bounds__(64) void finalize(
    const double* __restrict__ loss_part, float* __restrict__ out) {
  double v = loss_part[threadIdx.x];
  for (int o = 32; o > 0; o >>= 1) v += __shfl_down(v, o, 64);
  if (threadIdx.x == 0)
    out[LOSS_OFF] = (float)(v / 16777216.0);   // COMMITMENT_COST = 1.0
}

extern "C" void kernel_launch(void* const* d_in, const int* in_sizes, int n_in,
                              void* d_out, int out_size, void* d_ws, size_t ws_size,
                              hipStream_t stream) {
  const float* X = (const float*)d_in[0];   // [65536, 256]
  const float* E = (const float*)d_in[1];   // [1024, 256]
  float* out = (float*)d_out;
  char* ws = (char*)d_ws;

  int*    flag_count = (int*)(ws + 0);
  double* loss_part  = (double*)(ws + 8);
  double* enorm_d    = (double*)(ws + 520);
  float*  enorm_f    = (float*)(ws + 8712);
  int*    flag_rows  = (int*)(ws + 12808);
  int*    idx_ws     = (int*)(ws + 45576);

  hipLaunchKernelGGL(init_kernel, dim3(4), dim3(256), 0, stream,
                     E, enorm_d, enorm_f, flag_count, loss_part);
  hipLaunchKernelGGL(dist_argmin, dim3(NROWS / 128), dim3(256), 0, stream,
                     X, E, enorm_f, idx_ws, flag_count, flag_rows);
  hipLaunchKernelGGL(fixup, dim3(256), dim3(256), 0, stream,
                     X, E, enorm_d, flag_count, flag_rows, idx_ws);
  hipLaunchKernelGGL(gather_loss, dim3(NROWS / 16), dim3(256), 0, stream,
                     X, E, idx_ws, out, loss_part);
  hipLaunchKernelGGL(finalize, dim3(1), dim3(64), 0, stream, loss_part, out);
}